// Round 1
// baseline (157.058 us; speedup 1.0000x reference)
//
#include <hip/hip_runtime.h>

// Backward warp, bilinear sampling. B=16, H=W=1024, C=3, fp32.
// out(b,h,w,c) = sum of 4 corner samples of image at (h+flow.y, w+flow.x),
// with the reference's exact normalize round-trip, trunc-toward-zero corner
// indices, clamp-then-weight semantics.

__global__ __launch_bounds__(256) void backwarp_kernel(
    const float* __restrict__ image,
    const float* __restrict__ flow,
    float* __restrict__ out,
    int B, int H, int W) {
  int idx = blockIdx.x * blockDim.x + threadIdx.x;
  int total = B * H * W;
  if (idx >= total) return;

  int w  = idx % W;
  int hw = idx / W;
  int h  = hw % H;
  int b  = hw / H;

  float2 f = *reinterpret_cast<const float2*>(flow + (size_t)idx * 2);

  float Wf = (float)W, Hf = (float)H;
  float x = (float)w + f.x;
  float y = (float)h + f.y;
  // faithful round-trip from the reference (near-identity in fp32)
  x = 0.5f * (2.0f * (x / Wf - 0.5f) + 1.0f) * Wf;
  y = 0.5f * (2.0f * (y / Hf - 0.5f) + 1.0f) * Hf;

  // trunc toward zero, like astype(int32)
  int x0 = (int)x;
  int y0 = (int)y;
  int x1 = x0 + 1;
  int y1 = y0 + 1;
  x0 = min(max(x0, 0), W - 1);
  x1 = min(max(x1, 0), W - 1);
  y0 = min(max(y0, 0), H - 1);
  y1 = min(max(y1, 0), H - 1);

  float x0f = (float)x0, x1f = (float)x1;
  float y0f = (float)y0, y1f = (float)y1;
  float wa = (x1f - x) * (y1f - y);
  float wb = (x1f - x) * (y - y0f);
  float wc = (x - x0f) * (y1f - y);
  float wd = (x - x0f) * (y - y0f);

  size_t plane = (size_t)b * H * W;
  const float* pa = image + (plane + (size_t)y0 * W + x0) * 3;
  const float* pb = image + (plane + (size_t)y1 * W + x0) * 3;
  const float* pc = image + (plane + (size_t)y0 * W + x1) * 3;
  const float* pd = image + (plane + (size_t)y1 * W + x1) * 3;

  float* o = out + (size_t)idx * 3;
#pragma unroll
  for (int c = 0; c < 3; ++c) {
    o[c] = wa * pa[c] + wb * pb[c] + wc * pc[c] + wd * pd[c];
  }
}

extern "C" void kernel_launch(void* const* d_in, const int* in_sizes, int n_in,
                              void* d_out, int out_size, void* d_ws, size_t ws_size,
                              hipStream_t stream) {
  const float* image = (const float*)d_in[0];
  const float* flow  = (const float*)d_in[1];
  float* out = (float*)d_out;

  const int B = 16, H = 1024, W = 1024;
  int total = B * H * W;
  int block = 256;
  int grid = (total + block - 1) / block;
  backwarp_kernel<<<grid, block, 0, stream>>>(image, flow, out, B, H, W);
}